// Round 17
// baseline (91.905 us; speedup 1.0000x reference)
//
#include <hip/hip_runtime.h>

#define T_ 2
#define N_ 4096
#define E_ 4096
#define D_ 128
#define CAP 64        // max stored nnz per row/col
#define PAD 16        // unrolled gather width; tail handles c>16 (~0.3% rows)
#define SENT 8192     // sentinel row id (packs weight 0); extra zeroed row
#define UPR 64        // uints per bf16 feature row (128 bf16 = 64 uints)
#define W16S 65535.0f // fixed16 scale for packed dVis

// ---------------------------------------------------------------------------
// non-temporal load/store via clang ext_vector types (HIP_vector_type is not
// accepted by the builtin; ext vectors keep full dwordx4/x2 width + nt flag)
typedef float  f32x4 __attribute__((ext_vector_type(4)));
typedef float  f32x2 __attribute__((ext_vector_type(2)));
typedef unsigned u32x2 __attribute__((ext_vector_type(2)));

__device__ __forceinline__ float4 ntload4(const float4* p) {
    f32x4 v = __builtin_nontemporal_load((const f32x4*)p);
    float4 r; r.x = v.x; r.y = v.y; r.z = v.z; r.w = v.w;
    return r;
}
__device__ __forceinline__ void ntstore_u(unsigned* p, unsigned v) {
    __builtin_nontemporal_store(v, p);
}
__device__ __forceinline__ void ntstore_i(int* p, int v) {
    __builtin_nontemporal_store(v, p);
}
__device__ __forceinline__ void ntstore_u2(uint2* p, uint2 v) {
    u32x2 w; w.x = v.x; w.y = v.y;
    __builtin_nontemporal_store(w, (u32x2*)p);
}
__device__ __forceinline__ void ntstore_f2(float2* p, float2 v) {
    f32x2 w; w.x = v.x; w.y = v.y;
    __builtin_nontemporal_store(w, (f32x2*)p);
}

__device__ __forceinline__ unsigned f2bf_rne(float f) {
    unsigned u = __float_as_uint(f);
    return (u + 0x7FFFu + ((u >> 16) & 1u)) >> 16;
}
__device__ __forceinline__ unsigned pack2(float lo, float hi) {
    return f2bf_rne(lo) | (f2bf_rne(hi) << 16);
}

// unweighted 16-wide gather over UNPACKED int ids (adjNE; SENT rows are zero)
__device__ __forceinline__ float2 gather64(const unsigned* __restrict__ src,
        const int* __restrict__ row, int c, int lane) {
    const int4* r4 = (const int4*)row;
    int4 i0 = r4[0], i1 = r4[1], i2 = r4[2], i3 = r4[3];
    float sx = 0.f, sy = 0.f;
#define G1(id) { unsigned v = src[(size_t)(id) * UPR + lane]; \
                 sx += __uint_as_float(v << 16); \
                 sy += __uint_as_float(v & 0xFFFF0000u); }
    G1(i0.x) G1(i0.y) G1(i0.z) G1(i0.w)
    G1(i1.x) G1(i1.y) G1(i1.z) G1(i1.w)
    G1(i2.x) G1(i2.y) G1(i2.z) G1(i2.w)
    G1(i3.x) G1(i3.y) G1(i3.z) G1(i3.w)
    for (int j = PAD; j < c; ++j) G1(row[j])
#undef G1
    float2 r = {sx, sy};
    return r;
}

// unweighted 16-wide gather over PACKED entries (id low16; weight ignored)
__device__ __forceinline__ float2 gather16_id(const unsigned* __restrict__ src,
        const unsigned* __restrict__ row, int c, int lane) {
    const uint4* r4 = (const uint4*)row;
    uint4 i0 = r4[0], i1 = r4[1], i2 = r4[2], i3 = r4[3];
    float sx = 0.f, sy = 0.f;
#define G1(w) { unsigned v = src[(size_t)((w) & 0xFFFFu) * UPR + lane]; \
                sx += __uint_as_float(v << 16); \
                sy += __uint_as_float(v & 0xFFFF0000u); }
    G1(i0.x) G1(i0.y) G1(i0.z) G1(i0.w)
    G1(i1.x) G1(i1.y) G1(i1.z) G1(i1.w)
    G1(i2.x) G1(i2.y) G1(i2.z) G1(i2.w)
    G1(i3.x) G1(i3.y) G1(i3.z) G1(i3.w)
    for (int j = PAD; j < c; ++j) G1(row[j])
#undef G1
    float2 r = {sx, sy};
    return r;
}

// weighted 16-wide gather over PACKED entries (weight = hi16/W16S; SENT->w=0)
__device__ __forceinline__ float2 gather16_w(const unsigned* __restrict__ src,
        const unsigned* __restrict__ row, int c, int lane) {
    const uint4* r4 = (const uint4*)row;
    uint4 i0 = r4[0], i1 = r4[1], i2 = r4[2], i3 = r4[3];
    float sx = 0.f, sy = 0.f;
#define G1(w) { unsigned v = src[(size_t)((w) & 0xFFFFu) * UPR + lane]; \
                float wt = (float)((w) >> 16) * (1.0f / W16S); \
                sx += wt * __uint_as_float(v << 16); \
                sy += wt * __uint_as_float(v & 0xFFFF0000u); }
    G1(i0.x) G1(i0.y) G1(i0.z) G1(i0.w)
    G1(i1.x) G1(i1.y) G1(i1.z) G1(i1.w)
    G1(i2.x) G1(i2.y) G1(i2.z) G1(i2.w)
    G1(i3.x) G1(i3.y) G1(i3.z) G1(i3.w)
    for (int j = PAD; j < c; ++j) G1(row[j])
#undef G1
    float2 r = {sx, sy};
    return r;
}

// ---------------------------------------------------------------------------
// node 0: zero padded counters, prefill adjEN first-16 with SENT (packed w=0),
// zero the sentinel rows of ye2u/e2u.
__global__ void k_zero0(int* __restrict__ cntENp, unsigned* __restrict__ adjEN,
                        unsigned* __restrict__ ye2u, unsigned* __restrict__ e2u) {
    int i = blockIdx.x * 256 + threadIdx.x;     // grid 513 blocks
    if (i < (T_ * E_ + 1) * PAD) {
        int row = i >> 4, slot = i & 15;
        ntstore_u(&adjEN[(size_t)row * CAP + slot], (unsigned)SENT);
    }
    if (i <= T_ * E_) cntENp[i * 16] = 0;
    if (i < 64) {
        ntstore_u(&ye2u[(size_t)SENT * UPR + i], 0u);
        ntstore_u(&e2u[(size_t)SENT * UPR + i], 0u);
    }
}

// ---------------------------------------------------------------------------
// xw tile: y = xsrc @ W^T + b (UNSCALED; dVis folded into weighted ye gather)
__device__ __forceinline__ void xw_tile(int slot, int l,
        const float* __restrict__ xsrc, const float* __restrict__ W,
        const float* __restrict__ b, uint2* __restrict__ y2,
        float* s_xs, float* s_ws) {
    int t = slot >> 7;
    int nb = (slot >> 1) & 63, ob = slot & 1;
    int n0 = nb * 64, o0 = ob * 64;
    int tid = threadIdx.x;
    int tx = tid & 15, ty = tid >> 4;
    const float* Wg = W + ((size_t)(l * T_ + t) * D_ + o0) * D_;
    const float* xg = xsrc + (size_t)n0 * D_;
    float acc[4][4] = {};
    for (int kc = 0; kc < 4; ++kc) {
        __syncthreads();
        for (int i = tid; i < 512; i += 256) {
            int r = i >> 3, k4 = i & 7;
            *(float4*)(s_xs + r * 36 + k4 * 4) =
                *(const float4*)(xg + (size_t)r * D_ + kc * 32 + k4 * 4);
            int k4s = k4 ^ ((r >> 2) & 7);
            *(float4*)(s_ws + r * 32 + k4s * 4) =
                *(const float4*)(Wg + (size_t)r * D_ + kc * 32 + k4 * 4);
        }
        __syncthreads();
        #pragma unroll
        for (int k4 = 0; k4 < 8; ++k4) {
            float4 xv[4], wv[4];
            #pragma unroll
            for (int rr = 0; rr < 4; ++rr)
                xv[rr] = *(const float4*)(s_xs + (ty * 4 + rr) * 36 + k4 * 4);
            int k4s = k4 ^ (tx & 7);
            #pragma unroll
            for (int cc = 0; cc < 4; ++cc)
                wv[cc] = *(const float4*)(s_ws + (tx * 4 + cc) * 32 + k4s * 4);
            #pragma unroll
            for (int rr = 0; rr < 4; ++rr)
                #pragma unroll
                for (int cc = 0; cc < 4; ++cc)
                    acc[rr][cc] += xv[rr].x * wv[cc].x + xv[rr].y * wv[cc].y
                                 + xv[rr].z * wv[cc].z + xv[rr].w * wv[cc].w;
        }
    }
    const float* bg = b + (size_t)(l * T_ + t) * D_;
    float4 bv = *(const float4*)(bg + o0 + tx * 4);
    #pragma unroll
    for (int rr = 0; rr < 4; ++rr) {
        int n = n0 + ty * 4 + rr;
        uint2 ov;
        ov.x = pack2(acc[rr][0] + bv.x, acc[rr][1] + bv.y);
        ov.y = pack2(acc[rr][2] + bv.z, acc[rr][3] + bv.w);
        ntstore_u2(&y2[(size_t)(t * N_ + n) * (UPR / 2) + (o0 >> 2) + tx], ov);
    }
}

// ---------------------------------------------------------------------------
// node 1: scan+invert fused (blocks 0-2047) || xw layer 0 (blocks 2048-2303).
__global__ __launch_bounds__(256) void k_scan_inv_xw0(const float* __restrict__ H,
        float* __restrict__ dVis, int* __restrict__ cntNE,
        int* __restrict__ adjNE, int* __restrict__ cntENp,
        unsigned* __restrict__ adjEN,
        const float* __restrict__ x, const float* __restrict__ W,
        const float* __restrict__ b, uint2* __restrict__ y2) {
    __shared__ float s_xs[64 * 36];
    __shared__ float s_ws[64 * 32];
    int bid = blockIdx.x;
    if (bid >= 2048) {
        xw_tile(bid - 2048, 0, x, W, b, y2, s_xs, s_ws);
        return;
    }
    int row = bid * 4 + (threadIdx.x >> 6);   // t*N + n in [0,8192)
    int lane = threadIdx.x & 63;
    int t = row >> 12;
    const float4* row4 = (const float4*)(H + (size_t)row * E_);
    unsigned long long mask = 0;
    #pragma unroll
    for (int i = 0; i < 16; ++i) {
        float4 v = ntload4(&row4[i * 64 + lane]);   // read-once: bypass L2 retention
        unsigned mm = 0;
        if (v.x != 0.0f) mm |= 1u;
        if (v.y != 0.0f) mm |= 2u;
        if (v.z != 0.0f) mm |= 4u;
        if (v.w != 0.0f) mm |= 8u;
        mask |= (unsigned long long)mm << (i * 4);
    }
    int cnt = __popcll(mask);
    int incl = cnt;
    #pragma unroll
    for (int off = 1; off < 64; off <<= 1) {
        int u = __shfl_up(incl, off);
        if (lane >= off) incl += u;
    }
    int pos = incl - cnt;                      // exclusive prefix
    int total = __shfl(incl, 63);
    float dv = total > 0 ? rsqrtf((float)total) : 0.0f;
    unsigned packbase = (unsigned)row | ((unsigned)(dv * W16S + 0.5f) << 16);
    int* adjrow = adjNE + (size_t)row * CAP;
    unsigned long long m = mask;
    while (m) {
        int bpos = __builtin_ctzll(m);
        m &= m - 1;
        int e = ((bpos >> 2) << 8) + lane * 4 + (bpos & 3);
        int eg = t * E_ + e;                   // global edge id
        if (pos < CAP) ntstore_i(&adjrow[pos], eg);
        ++pos;
        int slot = atomicAdd(&cntENp[eg * 16], 1);
        if (slot < CAP) ntstore_u(&adjEN[(size_t)eg * CAP + slot], packbase);
    }
    if (lane < PAD - total) ntstore_i(&adjrow[total + lane], (int)SENT);
    if (lane == 63) {
        cntNE[row] = total < CAP ? total : CAP;
        dVis[row] = dv;
    }
}

// ---------------------------------------------------------------------------
// ye: dVis-weighted gather of unscaled y over packed adjEN. 64-lane units.
__global__ __launch_bounds__(256) void k_ye_w(const unsigned* __restrict__ y2u,
        const int* __restrict__ cntENp, const unsigned* __restrict__ adjEN,
        unsigned* __restrict__ ye2u) {
    int u = threadIdx.x >> 6, lane = threadIdx.x & 63;
    int vr = blockIdx.x * 4 + u;
    int c = cntENp[vr * 16];
    if (c > CAP) c = CAP;
    float dE = c > 0 ? 1.0f / (float)c : 0.0f;
    float2 g = gather16_w(y2u, adjEN + (size_t)vr * CAP, c, lane);
    ntstore_u(&ye2u[(size_t)vr * UPR + lane], pack2(dE * g.x, dE * g.y));
}

// o unit (unweighted gather of e over packed adjEN; cross-t via LDS)
__device__ __forceinline__ void o_unit(int e, int u, int lane,
        const unsigned* __restrict__ e2u, const int* __restrict__ cntENp,
        const unsigned* __restrict__ adjEN, float2* __restrict__ revacc2,
        float2* __restrict__ outrev2, int last, float2 (*sb)[64]) {
    int t = u & 1;
    int r = t * E_ + e;
    int c = cntENp[r * 16];
    if (c > CAP) c = CAP;
    float dE = c > 0 ? 1.0f / (float)c : 0.0f;
    float2 g = gather16_id(e2u, adjEN + (size_t)r * CAP, c, lane);
    float2 a = {dE * g.x, dE * g.y};
    sb[u][lane] = a;
    __syncthreads();
    if (t == 0) {
        float2 o2 = sb[u | 1][lane];
        float2 tot = {a.x + o2.x, a.y + o2.y};
        size_t i = (size_t)e * UPR + lane;
        if (!last) ntstore_f2(&revacc2[i], tot);
        else {
            float2 ra = revacc2[i];
            float2 o = {(ra.x + tot.x) * 0.5f, (ra.y + tot.y) * 0.5f};
            ntstore_f2(&outrev2[i], o);
        }
    }
}

// e: 64-lane units (t,n); gather ye over adjNE (unpacked ids); cross-t via LDS.
__global__ __launch_bounds__(256) void k_e(const unsigned* __restrict__ ye2u,
        const float* __restrict__ dVis, const int* __restrict__ cntNE,
        const int* __restrict__ adjNE, unsigned* __restrict__ e2u,
        const float* __restrict__ x0, float* __restrict__ xsum0,
        float* __restrict__ outnode, int last) {
    __shared__ float2 sb[4][64];
    int u = threadIdx.x >> 6, lane = threadIdx.x & 63;
    int t = u & 1;
    int n = blockIdx.x * 2 + (u >> 1);
    int r = t * N_ + n;
    int c = cntNE[r];
    float2 g = gather64(ye2u, adjNE + (size_t)r * CAP, c, lane);
    float dv = dVis[r];
    float e0 = dv * g.x; e0 = e0 >= 0.f ? e0 : 0.01f * e0;
    float e1 = dv * g.y; e1 = e1 >= 0.f ? e1 : 0.01f * e1;
    ntstore_u(&e2u[(size_t)r * UPR + lane], pack2(e0, e1));
    float2 mine = {e0, e1};
    sb[u][lane] = mine;
    __syncthreads();
    if (t == 0) {
        float2 o2 = sb[u | 1][lane];
        float2 xnew = {e0 + o2.x, e1 + o2.y};
        size_t i = (size_t)n * UPR + lane;
        if (!last) ntstore_f2(&((float2*)xsum0)[i], xnew);
        else {
            float2 xv = ((const float2*)x0)[i];
            float2 xs = ((const float2*)xsum0)[i];
            float2 o = {(xv.x + xs.x + xnew.x) * (1.0f / 3.0f),
                        (xv.y + xs.y + xnew.y) * (1.0f / 3.0f)};
            ntstore_f2(&((float2*)outnode)[i], o);
        }
    }
}

// node 4: xw layer 1 (blocks 0-255) || o layer 0 (blocks 256-2303).
__global__ __launch_bounds__(256) void k_xw1_o0(const float* __restrict__ xsum0,
        const float* __restrict__ W, const float* __restrict__ b,
        uint2* __restrict__ y2,
        const unsigned* __restrict__ e2u, const int* __restrict__ cntENp,
        const unsigned* __restrict__ adjEN, float* __restrict__ revacc) {
    __shared__ float s_xs[64 * 36];
    __shared__ float s_ws[64 * 32];
    __shared__ float2 sb[4][64];
    int bid = blockIdx.x;
    if (bid < 256) {
        xw_tile(bid, 1, xsum0, W, b, y2, s_xs, s_ws);
    } else {
        int u = threadIdx.x >> 6, lane = threadIdx.x & 63;
        int e = (bid - 256) * 2 + (u >> 1);
        o_unit(e, u, lane, e2u, cntENp, adjEN, (float2*)revacc, nullptr, 0, sb);
    }
}

// node 7: o layer 1.
__global__ __launch_bounds__(256) void k_o(const unsigned* __restrict__ e2u,
        const int* __restrict__ cntENp, const unsigned* __restrict__ adjEN,
        float* __restrict__ revacc, float* __restrict__ outrev) {
    __shared__ float2 sb[4][64];
    int u = threadIdx.x >> 6, lane = threadIdx.x & 63;
    int e = blockIdx.x * 2 + (u >> 1);
    o_unit(e, u, lane, e2u, cntENp, adjEN, (float2*)revacc, (float2*)outrev, 1, sb);
}

// ---------------------------------------------------------------------------
extern "C" void kernel_launch(void* const* d_in, const int* in_sizes, int n_in,
                              void* d_out, int out_size, void* d_ws, size_t ws_size,
                              hipStream_t stream) {
    const float* x = (const float*)d_in[0];
    const float* H = (const float*)d_in[1];
    const float* W = (const float*)d_in[2];
    const float* b = (const float*)d_in[3];
    float* outnode = (float*)d_out;
    float* outrev  = (float*)d_out + (size_t)N_ * D_;

    char* p = (char*)d_ws;
    auto alloc = [&](size_t bytes) {
        char* r = p;
        p += (bytes + 255) & ~(size_t)255;
        return r;
    };
    float*    dVis   = (float*)alloc(((size_t)T_ * N_ + 1) * 4);
    int*      cntNE  = (int*)  alloc((size_t)T_ * N_ * 4);
    int*      cntENp = (int*)  alloc(((size_t)T_ * E_ + 1) * 16 * 4);
    int*      adjNE  = (int*)  alloc((size_t)T_ * N_ * CAP * 4);
    unsigned* adjEN  = (unsigned*)alloc(((size_t)T_ * E_ + 1) * CAP * 4);
    unsigned* y2u    = (unsigned*)alloc((size_t)(SENT + 1) * UPR * 4);
    unsigned* ye2u   = (unsigned*)alloc((size_t)(SENT + 1) * UPR * 4);
    unsigned* e2u    = (unsigned*)alloc((size_t)(SENT + 1) * UPR * 4);
    float*    xsum0  = (float*)alloc((size_t)N_ * D_ * 4);
    float*    revacc = (float*)alloc((size_t)E_ * D_ * 4);

    // 8-node chain
    k_zero0<<<513, 256, 0, stream>>>(cntENp, adjEN, ye2u, e2u);
    k_scan_inv_xw0<<<2048 + 256, 256, 0, stream>>>(H, dVis, cntNE, adjNE,
            cntENp, adjEN, x, W, b, (uint2*)y2u);
    k_ye_w<<<2048, 256, 0, stream>>>(y2u, cntENp, adjEN, ye2u);
    k_e<<<2048, 256, 0, stream>>>(ye2u, dVis, cntNE, adjNE, e2u, x, xsum0,
                                  outnode, 0);
    k_xw1_o0<<<256 + 2048, 256, 0, stream>>>(xsum0, W, b, (uint2*)y2u,
            e2u, cntENp, adjEN, revacc);
    k_ye_w<<<2048, 256, 0, stream>>>(y2u, cntENp, adjEN, ye2u);
    k_e<<<2048, 256, 0, stream>>>(ye2u, dVis, cntNE, adjNE, e2u, x, xsum0,
                                  outnode, 1);
    k_o<<<2048, 256, 0, stream>>>(e2u, cntENp, adjEN, revacc, outrev);
}

// Round 18
// 78.535 us; speedup vs baseline: 1.1702x; 1.1702x over previous
//
#include <hip/hip_runtime.h>

#define T_ 2
#define N_ 4096
#define E_ 4096
#define D_ 128
#define CAP 64        // max stored nnz per row/col
#define PAD 16        // unrolled gather width; tail handles c>16 (~0.3% rows)
#define SENT 8192     // sentinel row id (packs weight 0); extra zeroed row
#define UPR 64        // uints per bf16 feature row (128 bf16 = 64 uints)
#define W16S 65535.0f // fixed16 scale for packed dVis

// ---------------------------------------------------------------------------
__device__ __forceinline__ unsigned f2bf_rne(float f) {
    unsigned u = __float_as_uint(f);
    return (u + 0x7FFFu + ((u >> 16) & 1u)) >> 16;
}
__device__ __forceinline__ unsigned pack2(float lo, float hi) {
    return f2bf_rne(lo) | (f2bf_rne(hi) << 16);
}

// unweighted 16-wide gather over UNPACKED int ids (adjNE; SENT rows are zero)
__device__ __forceinline__ float2 gather64(const unsigned* __restrict__ src,
        const int* __restrict__ row, int c, int lane) {
    const int4* r4 = (const int4*)row;
    int4 i0 = r4[0], i1 = r4[1], i2 = r4[2], i3 = r4[3];
    float sx = 0.f, sy = 0.f;
#define G1(id) { unsigned v = src[(size_t)(id) * UPR + lane]; \
                 sx += __uint_as_float(v << 16); \
                 sy += __uint_as_float(v & 0xFFFF0000u); }
    G1(i0.x) G1(i0.y) G1(i0.z) G1(i0.w)
    G1(i1.x) G1(i1.y) G1(i1.z) G1(i1.w)
    G1(i2.x) G1(i2.y) G1(i2.z) G1(i2.w)
    G1(i3.x) G1(i3.y) G1(i3.z) G1(i3.w)
    for (int j = PAD; j < c; ++j) G1(row[j])
#undef G1
    float2 r = {sx, sy};
    return r;
}

// unweighted 16-wide gather over PACKED entries (id low16; weight ignored)
__device__ __forceinline__ float2 gather16_id(const unsigned* __restrict__ src,
        const unsigned* __restrict__ row, int c, int lane) {
    const uint4* r4 = (const uint4*)row;
    uint4 i0 = r4[0], i1 = r4[1], i2 = r4[2], i3 = r4[3];
    float sx = 0.f, sy = 0.f;
#define G1(w) { unsigned v = src[(size_t)((w) & 0xFFFFu) * UPR + lane]; \
                sx += __uint_as_float(v << 16); \
                sy += __uint_as_float(v & 0xFFFF0000u); }
    G1(i0.x) G1(i0.y) G1(i0.z) G1(i0.w)
    G1(i1.x) G1(i1.y) G1(i1.z) G1(i1.w)
    G1(i2.x) G1(i2.y) G1(i2.z) G1(i2.w)
    G1(i3.x) G1(i3.y) G1(i3.z) G1(i3.w)
    for (int j = PAD; j < c; ++j) G1(row[j])
#undef G1
    float2 r = {sx, sy};
    return r;
}

// weighted 16-wide gather over PACKED entries (weight = hi16/W16S; SENT->w=0)
__device__ __forceinline__ float2 gather16_w(const unsigned* __restrict__ src,
        const unsigned* __restrict__ row, int c, int lane) {
    const uint4* r4 = (const uint4*)row;
    uint4 i0 = r4[0], i1 = r4[1], i2 = r4[2], i3 = r4[3];
    float sx = 0.f, sy = 0.f;
#define G1(w) { unsigned v = src[(size_t)((w) & 0xFFFFu) * UPR + lane]; \
                float wt = (float)((w) >> 16) * (1.0f / W16S); \
                sx += wt * __uint_as_float(v << 16); \
                sy += wt * __uint_as_float(v & 0xFFFF0000u); }
    G1(i0.x) G1(i0.y) G1(i0.z) G1(i0.w)
    G1(i1.x) G1(i1.y) G1(i1.z) G1(i1.w)
    G1(i2.x) G1(i2.y) G1(i2.z) G1(i2.w)
    G1(i3.x) G1(i3.y) G1(i3.z) G1(i3.w)
    for (int j = PAD; j < c; ++j) G1(row[j])
#undef G1
    float2 r = {sx, sy};
    return r;
}

// ---------------------------------------------------------------------------
// node 0: zero padded counters, prefill adjEN first-16 with SENT (packed w=0),
// zero the sentinel rows of ye2u/e2u.
__global__ void k_zero0(int* __restrict__ cntENp, unsigned* __restrict__ adjEN,
                        unsigned* __restrict__ ye2u, unsigned* __restrict__ e2u) {
    int i = blockIdx.x * 256 + threadIdx.x;     // grid 513 blocks
    if (i < (T_ * E_ + 1) * PAD) {
        int row = i >> 4, slot = i & 15;
        adjEN[(size_t)row * CAP + slot] = SENT; // id=SENT, weight=0
    }
    if (i <= T_ * E_) cntENp[i * 16] = 0;
    if (i < 64) {
        ye2u[(size_t)SENT * UPR + i] = 0u;
        e2u[(size_t)SENT * UPR + i] = 0u;
    }
}

// ---------------------------------------------------------------------------
// xw tile, 32x32: y[t, n0:+32, o0:+32] = xsrc @ W[l,t]^T + b (UNSCALED).
// 1024 tiles/layer (4 blocks/CU during the xw phase -> short straggler tail).
// 256 threads = 16x16, each computes 2x2 outputs; K-chunk 32 via LDS (8.7KB).
__device__ __forceinline__ void xw_tile32(int slot, int l,
        const float* __restrict__ xsrc, const float* __restrict__ W,
        const float* __restrict__ b, unsigned* __restrict__ y2u,
        float* s_xs, float* s_ws) {
    int t = slot >> 9;                 // 512 tiles per type
    int nb = (slot >> 2) & 127, ob = slot & 3;
    int n0 = nb * 32, o0 = ob * 32;
    int tid = threadIdx.x;
    int tx = tid & 15, ty = tid >> 4;
    const float* Wg = W + ((size_t)(l * T_ + t) * D_ + o0) * D_;
    const float* xg = xsrc + (size_t)n0 * D_;
    float acc[2][2] = {};
    for (int kc = 0; kc < 4; ++kc) {
        __syncthreads();
        {   // 32 rows x 32 k each for xs and ws: 256 float4 each, 1 per thread
            int r = tid >> 3, k4 = tid & 7;
            *(float4*)(s_xs + r * 36 + k4 * 4) =
                *(const float4*)(xg + (size_t)r * D_ + kc * 32 + k4 * 4);
            int k4s = k4 ^ ((r >> 2) & 7);
            *(float4*)(s_ws + r * 32 + k4s * 4) =
                *(const float4*)(Wg + (size_t)r * D_ + kc * 32 + k4 * 4);
        }
        __syncthreads();
        #pragma unroll
        for (int k4 = 0; k4 < 8; ++k4) {
            float4 xv[2], wv[2];
            #pragma unroll
            for (int rr = 0; rr < 2; ++rr)
                xv[rr] = *(const float4*)(s_xs + (ty * 2 + rr) * 36 + k4 * 4);
            #pragma unroll
            for (int cc = 0; cc < 2; ++cc) {
                int row = tx * 2 + cc;
                int k4s = k4 ^ ((row >> 2) & 7);
                wv[cc] = *(const float4*)(s_ws + row * 32 + k4s * 4);
            }
            #pragma unroll
            for (int rr = 0; rr < 2; ++rr)
                #pragma unroll
                for (int cc = 0; cc < 2; ++cc)
                    acc[rr][cc] += xv[rr].x * wv[cc].x + xv[rr].y * wv[cc].y
                                 + xv[rr].z * wv[cc].z + xv[rr].w * wv[cc].w;
        }
    }
    const float* bg = b + (size_t)(l * T_ + t) * D_ + o0;
    float b0 = bg[tx * 2], b1 = bg[tx * 2 + 1];
    #pragma unroll
    for (int rr = 0; rr < 2; ++rr) {
        int n = n0 + ty * 2 + rr;
        unsigned ov = pack2(acc[rr][0] + b0, acc[rr][1] + b1);
        y2u[(size_t)(t * N_ + n) * UPR + (o0 >> 1) + tx] = ov;
    }
}

// ---------------------------------------------------------------------------
// node 1: scan+invert fused (blocks 0-2047) || xw layer 0 (blocks 2048-3071).
__global__ __launch_bounds__(256) void k_scan_inv_xw0(const float* __restrict__ H,
        float* __restrict__ dVis, int* __restrict__ cntNE,
        int* __restrict__ adjNE, int* __restrict__ cntENp,
        unsigned* __restrict__ adjEN,
        const float* __restrict__ x, const float* __restrict__ W,
        const float* __restrict__ b, unsigned* __restrict__ y2u) {
    __shared__ float s_xs[32 * 36];
    __shared__ float s_ws[32 * 32];
    int bid = blockIdx.x;
    if (bid >= 2048) {
        xw_tile32(bid - 2048, 0, x, W, b, y2u, s_xs, s_ws);
        return;
    }
    int row = bid * 4 + (threadIdx.x >> 6);   // t*N + n in [0,8192)
    int lane = threadIdx.x & 63;
    int t = row >> 12;
    const float4* row4 = (const float4*)(H + (size_t)row * E_);
    unsigned long long mask = 0;
    #pragma unroll
    for (int i = 0; i < 16; ++i) {
        float4 v = row4[i * 64 + lane];       // 1KB/instr coalesced
        unsigned mm = 0;
        if (v.x != 0.0f) mm |= 1u;
        if (v.y != 0.0f) mm |= 2u;
        if (v.z != 0.0f) mm |= 4u;
        if (v.w != 0.0f) mm |= 8u;
        mask |= (unsigned long long)mm << (i * 4);
    }
    int cnt = __popcll(mask);
    int incl = cnt;
    #pragma unroll
    for (int off = 1; off < 64; off <<= 1) {
        int u = __shfl_up(incl, off);
        if (lane >= off) incl += u;
    }
    int pos = incl - cnt;                      // exclusive prefix
    int total = __shfl(incl, 63);
    float dv = total > 0 ? rsqrtf((float)total) : 0.0f;
    unsigned packbase = (unsigned)row | ((unsigned)(dv * W16S + 0.5f) << 16);
    int* adjrow = adjNE + (size_t)row * CAP;
    unsigned long long m = mask;
    while (m) {
        int bpos = __builtin_ctzll(m);
        m &= m - 1;
        int e = ((bpos >> 2) << 8) + lane * 4 + (bpos & 3);
        int eg = t * E_ + e;                   // global edge id
        if (pos < CAP) adjrow[pos] = eg;
        ++pos;
        int slot = atomicAdd(&cntENp[eg * 16], 1);
        if (slot < CAP) adjEN[(size_t)eg * CAP + slot] = packbase;
    }
    if (lane < PAD - total) adjrow[total + lane] = SENT;   // pad to 16
    if (lane == 63) {
        cntNE[row] = total < CAP ? total : CAP;
        dVis[row] = dv;
    }
}

// ---------------------------------------------------------------------------
// ye: dVis-weighted gather of unscaled y over packed adjEN. 64-lane units.
__global__ __launch_bounds__(256) void k_ye_w(const unsigned* __restrict__ y2u,
        const int* __restrict__ cntENp, const unsigned* __restrict__ adjEN,
        unsigned* __restrict__ ye2u) {
    int u = threadIdx.x >> 6, lane = threadIdx.x & 63;
    int vr = blockIdx.x * 4 + u;
    int c = cntENp[vr * 16];
    if (c > CAP) c = CAP;
    float dE = c > 0 ? 1.0f / (float)c : 0.0f;
    float2 g = gather16_w(y2u, adjEN + (size_t)vr * CAP, c, lane);
    ye2u[(size_t)vr * UPR + lane] = pack2(dE * g.x, dE * g.y);
}

// o unit (unweighted gather of e over packed adjEN; cross-t via LDS)
__device__ __forceinline__ void o_unit(int e, int u, int lane,
        const unsigned* __restrict__ e2u, const int* __restrict__ cntENp,
        const unsigned* __restrict__ adjEN, float2* __restrict__ revacc2,
        float2* __restrict__ outrev2, int last, float2 (*sb)[64]) {
    int t = u & 1;
    int r = t * E_ + e;
    int c = cntENp[r * 16];
    if (c > CAP) c = CAP;
    float dE = c > 0 ? 1.0f / (float)c : 0.0f;
    float2 g = gather16_id(e2u, adjEN + (size_t)r * CAP, c, lane);
    float2 a = {dE * g.x, dE * g.y};
    sb[u][lane] = a;
    __syncthreads();
    if (t == 0) {
        float2 o2 = sb[u | 1][lane];
        float2 tot = {a.x + o2.x, a.y + o2.y};
        size_t i = (size_t)e * UPR + lane;
        if (!last) revacc2[i] = tot;
        else {
            float2 ra = revacc2[i];
            float2 o = {(ra.x + tot.x) * 0.5f, (ra.y + tot.y) * 0.5f};
            outrev2[i] = o;
        }
    }
}

// e: 64-lane units (t,n); gather ye over adjNE (unpacked ids); cross-t via LDS.
__global__ __launch_bounds__(256) void k_e(const unsigned* __restrict__ ye2u,
        const float* __restrict__ dVis, const int* __restrict__ cntNE,
        const int* __restrict__ adjNE, unsigned* __restrict__ e2u,
        const float* __restrict__ x0, float* __restrict__ xsum0,
        float* __restrict__ outnode, int last) {
    __shared__ float2 sb[4][64];
    int u = threadIdx.x >> 6, lane = threadIdx.x & 63;
    int t = u & 1;
    int n = blockIdx.x * 2 + (u >> 1);
    int r = t * N_ + n;
    int c = cntNE[r];
    float2 g = gather64(ye2u, adjNE + (size_t)r * CAP, c, lane);
    float dv = dVis[r];
    float e0 = dv * g.x; e0 = e0 >= 0.f ? e0 : 0.01f * e0;
    float e1 = dv * g.y; e1 = e1 >= 0.f ? e1 : 0.01f * e1;
    e2u[(size_t)r * UPR + lane] = pack2(e0, e1);
    float2 mine = {e0, e1};
    sb[u][lane] = mine;
    __syncthreads();
    if (t == 0) {
        float2 o2 = sb[u | 1][lane];
        float2 xnew = {e0 + o2.x, e1 + o2.y};
        size_t i = (size_t)n * UPR + lane;
        if (!last) ((float2*)xsum0)[i] = xnew;
        else {
            float2 xv = ((const float2*)x0)[i];
            float2 xs = ((const float2*)xsum0)[i];
            float2 o = {(xv.x + xs.x + xnew.x) * (1.0f / 3.0f),
                        (xv.y + xs.y + xnew.y) * (1.0f / 3.0f)};
            ((float2*)outnode)[i] = o;
        }
    }
}

// node 4: xw layer 1 (blocks 0-1023) || o layer 0 (blocks 1024-3071).
__global__ __launch_bounds__(256) void k_xw1_o0(const float* __restrict__ xsum0,
        const float* __restrict__ W, const float* __restrict__ b,
        unsigned* __restrict__ y2u,
        const unsigned* __restrict__ e2u, const int* __restrict__ cntENp,
        const unsigned* __restrict__ adjEN, float* __restrict__ revacc) {
    __shared__ float s_xs[32 * 36];
    __shared__ float s_ws[32 * 32];
    __shared__ float2 sb[4][64];
    int bid = blockIdx.x;
    if (bid < 1024) {
        xw_tile32(bid, 1, xsum0, W, b, y2u, s_xs, s_ws);
    } else {
        int u = threadIdx.x >> 6, lane = threadIdx.x & 63;
        int e = (bid - 1024) * 2 + (u >> 1);
        o_unit(e, u, lane, e2u, cntENp, adjEN, (float2*)revacc, nullptr, 0, sb);
    }
}

// node 7: o layer 1.
__global__ __launch_bounds__(256) void k_o(const unsigned* __restrict__ e2u,
        const int* __restrict__ cntENp, const unsigned* __restrict__ adjEN,
        float* __restrict__ revacc, float* __restrict__ outrev) {
    __shared__ float2 sb[4][64];
    int u = threadIdx.x >> 6, lane = threadIdx.x & 63;
    int e = blockIdx.x * 2 + (u >> 1);
    o_unit(e, u, lane, e2u, cntENp, adjEN, (float2*)revacc, (float2*)outrev, 1, sb);
}

// ---------------------------------------------------------------------------
extern "C" void kernel_launch(void* const* d_in, const int* in_sizes, int n_in,
                              void* d_out, int out_size, void* d_ws, size_t ws_size,
                              hipStream_t stream) {
    const float* x = (const float*)d_in[0];
    const float* H = (const float*)d_in[1];
    const float* W = (const float*)d_in[2];
    const float* b = (const float*)d_in[3];
    float* outnode = (float*)d_out;
    float* outrev  = (float*)d_out + (size_t)N_ * D_;

    char* p = (char*)d_ws;
    auto alloc = [&](size_t bytes) {
        char* r = p;
        p += (bytes + 255) & ~(size_t)255;
        return r;
    };
    float*    dVis   = (float*)alloc(((size_t)T_ * N_ + 1) * 4);
    int*      cntNE  = (int*)  alloc((size_t)T_ * N_ * 4);
    int*      cntENp = (int*)  alloc(((size_t)T_ * E_ + 1) * 16 * 4);
    int*      adjNE  = (int*)  alloc((size_t)T_ * N_ * CAP * 4);
    unsigned* adjEN  = (unsigned*)alloc(((size_t)T_ * E_ + 1) * CAP * 4);
    unsigned* y2u    = (unsigned*)alloc((size_t)(SENT + 1) * UPR * 4);
    unsigned* ye2u   = (unsigned*)alloc((size_t)(SENT + 1) * UPR * 4);
    unsigned* e2u    = (unsigned*)alloc((size_t)(SENT + 1) * UPR * 4);
    float*    xsum0  = (float*)alloc((size_t)N_ * D_ * 4);
    float*    revacc = (float*)alloc((size_t)E_ * D_ * 4);

    // 8-node chain
    k_zero0<<<513, 256, 0, stream>>>(cntENp, adjEN, ye2u, e2u);
    k_scan_inv_xw0<<<2048 + 1024, 256, 0, stream>>>(H, dVis, cntNE, adjNE,
            cntENp, adjEN, x, W, b, y2u);
    k_ye_w<<<2048, 256, 0, stream>>>(y2u, cntENp, adjEN, ye2u);
    k_e<<<2048, 256, 0, stream>>>(ye2u, dVis, cntNE, adjNE, e2u, x, xsum0,
                                  outnode, 0);
    k_xw1_o0<<<1024 + 2048, 256, 0, stream>>>(xsum0, W, b, y2u,
            e2u, cntENp, adjEN, revacc);
    k_ye_w<<<2048, 256, 0, stream>>>(y2u, cntENp, adjEN, ye2u);
    k_e<<<2048, 256, 0, stream>>>(ye2u, dVis, cntNE, adjNE, e2u, x, xsum0,
                                  outnode, 1);
    k_o<<<2048, 256, 0, stream>>>(e2u, cntENp, adjEN, revacc, outrev);
}

// Round 19
// 78.372 us; speedup vs baseline: 1.1727x; 1.0021x over previous
//
#include <hip/hip_runtime.h>

#define T_ 2
#define N_ 4096
#define E_ 4096
#define D_ 128
#define CAP 64        // max stored nnz per row/col
#define PAD 16        // unrolled gather width; tail handles c>16 (~0.3% rows)
#define SENT 8192     // sentinel row id (packs weight 0); extra zeroed row
#define UPR 64        // uints per bf16 feature row (128 bf16 = 64 uints)
#define W16S 65535.0f // fixed16 scale for packed dVis

// ---------------------------------------------------------------------------
__device__ __forceinline__ unsigned f2bf_rne(float f) {
    unsigned u = __float_as_uint(f);
    return (u + 0x7FFFu + ((u >> 16) & 1u)) >> 16;
}
__device__ __forceinline__ unsigned pack2(float lo, float hi) {
    return f2bf_rne(lo) | (f2bf_rne(hi) << 16);
}

// unweighted 16-wide gather over UNPACKED int ids (adjNE; SENT rows are zero)
__device__ __forceinline__ float2 gather64(const unsigned* __restrict__ src,
        const int* __restrict__ row, int c, int lane) {
    const int4* r4 = (const int4*)row;
    int4 i0 = r4[0], i1 = r4[1], i2 = r4[2], i3 = r4[3];
    float sx = 0.f, sy = 0.f;
#define G1(id) { unsigned v = src[(size_t)(id) * UPR + lane]; \
                 sx += __uint_as_float(v << 16); \
                 sy += __uint_as_float(v & 0xFFFF0000u); }
    G1(i0.x) G1(i0.y) G1(i0.z) G1(i0.w)
    G1(i1.x) G1(i1.y) G1(i1.z) G1(i1.w)
    G1(i2.x) G1(i2.y) G1(i2.z) G1(i2.w)
    G1(i3.x) G1(i3.y) G1(i3.z) G1(i3.w)
    for (int j = PAD; j < c; ++j) G1(row[j])
#undef G1
    float2 r = {sx, sy};
    return r;
}

// unweighted 16-wide gather over PACKED entries (id low16; weight ignored)
__device__ __forceinline__ float2 gather16_id(const unsigned* __restrict__ src,
        const unsigned* __restrict__ row, int c, int lane) {
    const uint4* r4 = (const uint4*)row;
    uint4 i0 = r4[0], i1 = r4[1], i2 = r4[2], i3 = r4[3];
    float sx = 0.f, sy = 0.f;
#define G1(w) { unsigned v = src[(size_t)((w) & 0xFFFFu) * UPR + lane]; \
                sx += __uint_as_float(v << 16); \
                sy += __uint_as_float(v & 0xFFFF0000u); }
    G1(i0.x) G1(i0.y) G1(i0.z) G1(i0.w)
    G1(i1.x) G1(i1.y) G1(i1.z) G1(i1.w)
    G1(i2.x) G1(i2.y) G1(i2.z) G1(i2.w)
    G1(i3.x) G1(i3.y) G1(i3.z) G1(i3.w)
    for (int j = PAD; j < c; ++j) G1(row[j])
#undef G1
    float2 r = {sx, sy};
    return r;
}

// weighted 16-wide gather over PACKED entries (weight = hi16/W16S; SENT->w=0)
__device__ __forceinline__ float2 gather16_w(const unsigned* __restrict__ src,
        const unsigned* __restrict__ row, int c, int lane) {
    const uint4* r4 = (const uint4*)row;
    uint4 i0 = r4[0], i1 = r4[1], i2 = r4[2], i3 = r4[3];
    float sx = 0.f, sy = 0.f;
#define G1(w) { unsigned v = src[(size_t)((w) & 0xFFFFu) * UPR + lane]; \
                float wt = (float)((w) >> 16) * (1.0f / W16S); \
                sx += wt * __uint_as_float(v << 16); \
                sy += wt * __uint_as_float(v & 0xFFFF0000u); }
    G1(i0.x) G1(i0.y) G1(i0.z) G1(i0.w)
    G1(i1.x) G1(i1.y) G1(i1.z) G1(i1.w)
    G1(i2.x) G1(i2.y) G1(i2.z) G1(i2.w)
    G1(i3.x) G1(i3.y) G1(i3.z) G1(i3.w)
    for (int j = PAD; j < c; ++j) G1(row[j])
#undef G1
    float2 r = {sx, sy};
    return r;
}

// ---------------------------------------------------------------------------
// node 0: zero padded counters, prefill adjEN first-16 with SENT (packed w=0),
// zero the sentinel rows of ye2u/e2u.
__global__ void k_zero0(int* __restrict__ cntENp, unsigned* __restrict__ adjEN,
                        unsigned* __restrict__ ye2u, unsigned* __restrict__ e2u) {
    int i = blockIdx.x * 256 + threadIdx.x;     // grid 513 blocks
    if (i < (T_ * E_ + 1) * PAD) {
        int row = i >> 4, slot = i & 15;
        adjEN[(size_t)row * CAP + slot] = SENT; // id=SENT, weight=0
    }
    if (i <= T_ * E_) cntENp[i * 16] = 0;
    if (i < 64) {
        ye2u[(size_t)SENT * UPR + i] = 0u;
        e2u[(size_t)SENT * UPR + i] = 0u;
    }
}

// ---------------------------------------------------------------------------
// xw tile, 32x32: y[t, n0:+32, o0:+32] = xsrc @ W[l,t]^T + b (UNSCALED).
// 1024 tiles/layer; 256 threads = 16x16, 2x2 outputs each; K-chunk 32 (8.7KB LDS).
__device__ __forceinline__ void xw_tile32(int slot, int l,
        const float* __restrict__ xsrc, const float* __restrict__ W,
        const float* __restrict__ b, unsigned* __restrict__ y2u,
        float* s_xs, float* s_ws) {
    int t = slot >> 9;                 // 512 tiles per type
    int nb = (slot >> 2) & 127, ob = slot & 3;
    int n0 = nb * 32, o0 = ob * 32;
    int tid = threadIdx.x;
    int tx = tid & 15, ty = tid >> 4;
    const float* Wg = W + ((size_t)(l * T_ + t) * D_ + o0) * D_;
    const float* xg = xsrc + (size_t)n0 * D_;
    float acc[2][2] = {};
    for (int kc = 0; kc < 4; ++kc) {
        __syncthreads();
        {
            int r = tid >> 3, k4 = tid & 7;
            *(float4*)(s_xs + r * 36 + k4 * 4) =
                *(const float4*)(xg + (size_t)r * D_ + kc * 32 + k4 * 4);
            int k4s = k4 ^ ((r >> 2) & 7);
            *(float4*)(s_ws + r * 32 + k4s * 4) =
                *(const float4*)(Wg + (size_t)r * D_ + kc * 32 + k4 * 4);
        }
        __syncthreads();
        #pragma unroll
        for (int k4 = 0; k4 < 8; ++k4) {
            float4 xv[2], wv[2];
            #pragma unroll
            for (int rr = 0; rr < 2; ++rr)
                xv[rr] = *(const float4*)(s_xs + (ty * 2 + rr) * 36 + k4 * 4);
            #pragma unroll
            for (int cc = 0; cc < 2; ++cc) {
                int row = tx * 2 + cc;
                int k4s = k4 ^ ((row >> 2) & 7);
                wv[cc] = *(const float4*)(s_ws + row * 32 + k4s * 4);
            }
            #pragma unroll
            for (int rr = 0; rr < 2; ++rr)
                #pragma unroll
                for (int cc = 0; cc < 2; ++cc)
                    acc[rr][cc] += xv[rr].x * wv[cc].x + xv[rr].y * wv[cc].y
                                 + xv[rr].z * wv[cc].z + xv[rr].w * wv[cc].w;
        }
    }
    const float* bg = b + (size_t)(l * T_ + t) * D_ + o0;
    float b0 = bg[tx * 2], b1 = bg[tx * 2 + 1];
    #pragma unroll
    for (int rr = 0; rr < 2; ++rr) {
        int n = n0 + ty * 2 + rr;
        unsigned ov = pack2(acc[rr][0] + b0, acc[rr][1] + b1);
        y2u[(size_t)(t * N_ + n) * UPR + (o0 >> 1) + tx] = ov;
    }
}

// ---------------------------------------------------------------------------
// node 1: scan+invert fused (blocks 0-2047) || xw layer 0 (blocks 2048-3071).
__global__ __launch_bounds__(256) void k_scan_inv_xw0(const float* __restrict__ H,
        float* __restrict__ dVis, int* __restrict__ cntNE,
        int* __restrict__ adjNE, int* __restrict__ cntENp,
        unsigned* __restrict__ adjEN,
        const float* __restrict__ x, const float* __restrict__ W,
        const float* __restrict__ b, unsigned* __restrict__ y2u) {
    __shared__ float s_xs[32 * 36];
    __shared__ float s_ws[32 * 32];
    int bid = blockIdx.x;
    if (bid >= 2048) {
        xw_tile32(bid - 2048, 0, x, W, b, y2u, s_xs, s_ws);
        return;
    }
    int row = bid * 4 + (threadIdx.x >> 6);   // t*N + n in [0,8192)
    int lane = threadIdx.x & 63;
    int t = row >> 12;
    const float4* row4 = (const float4*)(H + (size_t)row * E_);
    unsigned long long mask = 0;
    #pragma unroll
    for (int i = 0; i < 16; ++i) {
        float4 v = row4[i * 64 + lane];       // 1KB/instr coalesced
        unsigned mm = 0;
        if (v.x != 0.0f) mm |= 1u;
        if (v.y != 0.0f) mm |= 2u;
        if (v.z != 0.0f) mm |= 4u;
        if (v.w != 0.0f) mm |= 8u;
        mask |= (unsigned long long)mm << (i * 4);
    }
    int cnt = __popcll(mask);
    int incl = cnt;
    #pragma unroll
    for (int off = 1; off < 64; off <<= 1) {
        int u = __shfl_up(incl, off);
        if (lane >= off) incl += u;
    }
    int pos = incl - cnt;                      // exclusive prefix
    int total = __shfl(incl, 63);
    float dv = total > 0 ? rsqrtf((float)total) : 0.0f;
    unsigned packbase = (unsigned)row | ((unsigned)(dv * W16S + 0.5f) << 16);
    int* adjrow = adjNE + (size_t)row * CAP;
    unsigned long long m = mask;
    while (m) {
        int bpos = __builtin_ctzll(m);
        m &= m - 1;
        int e = ((bpos >> 2) << 8) + lane * 4 + (bpos & 3);
        int eg = t * E_ + e;                   // global edge id
        if (pos < CAP) adjrow[pos] = eg;
        ++pos;
        int slot = atomicAdd(&cntENp[eg * 16], 1);
        if (slot < CAP) adjEN[(size_t)eg * CAP + slot] = packbase;
    }
    if (lane < PAD - total) adjrow[total + lane] = SENT;   // pad to 16
    if (lane == 63) {
        cntNE[row] = total < CAP ? total : CAP;
        dVis[row] = dv;
    }
}

// ---------------------------------------------------------------------------
// ye layer 0: dVis-weighted gather of unscaled y; ALSO writes dense cntEN
// (16x fewer cold counter lines for the 3 later consumers o0/ye1/o1).
__global__ __launch_bounds__(256) void k_ye_w0(const unsigned* __restrict__ y2u,
        const int* __restrict__ cntENp, const unsigned* __restrict__ adjEN,
        unsigned* __restrict__ ye2u, int* __restrict__ cntEN) {
    int u = threadIdx.x >> 6, lane = threadIdx.x & 63;
    int vr = blockIdx.x * 4 + u;
    int c = cntENp[vr * 16];
    if (c > CAP) c = CAP;
    if (lane == 0) cntEN[vr] = c;
    float dE = c > 0 ? 1.0f / (float)c : 0.0f;
    float2 g = gather16_w(y2u, adjEN + (size_t)vr * CAP, c, lane);
    ye2u[(size_t)vr * UPR + lane] = pack2(dE * g.x, dE * g.y);
}

// ye layer 1: reads dense cntEN.
__global__ __launch_bounds__(256) void k_ye_w1(const unsigned* __restrict__ y2u,
        const int* __restrict__ cntEN, const unsigned* __restrict__ adjEN,
        unsigned* __restrict__ ye2u) {
    int u = threadIdx.x >> 6, lane = threadIdx.x & 63;
    int vr = blockIdx.x * 4 + u;
    int c = cntEN[vr];
    float dE = c > 0 ? 1.0f / (float)c : 0.0f;
    float2 g = gather16_w(y2u, adjEN + (size_t)vr * CAP, c, lane);
    ye2u[(size_t)vr * UPR + lane] = pack2(dE * g.x, dE * g.y);
}

// o unit (unweighted gather of e over packed adjEN; dense counts; LDS cross-t)
__device__ __forceinline__ void o_unit(int e, int u, int lane,
        const unsigned* __restrict__ e2u, const int* __restrict__ cntEN,
        const unsigned* __restrict__ adjEN, float2* __restrict__ revacc2,
        float2* __restrict__ outrev2, int last, float2 (*sb)[64]) {
    int t = u & 1;
    int r = t * E_ + e;
    int c = cntEN[r];
    float dE = c > 0 ? 1.0f / (float)c : 0.0f;
    float2 g = gather16_id(e2u, adjEN + (size_t)r * CAP, c, lane);
    float2 a = {dE * g.x, dE * g.y};
    sb[u][lane] = a;
    __syncthreads();
    if (t == 0) {
        float2 o2 = sb[u | 1][lane];
        float2 tot = {a.x + o2.x, a.y + o2.y};
        size_t i = (size_t)e * UPR + lane;
        if (!last) revacc2[i] = tot;
        else {
            float2 ra = revacc2[i];
            float2 o = {(ra.x + tot.x) * 0.5f, (ra.y + tot.y) * 0.5f};
            outrev2[i] = o;
        }
    }
}

// e: 64-lane units (t,n); gather ye over adjNE (unpacked ids); cross-t via LDS.
__global__ __launch_bounds__(256) void k_e(const unsigned* __restrict__ ye2u,
        const float* __restrict__ dVis, const int* __restrict__ cntNE,
        const int* __restrict__ adjNE, unsigned* __restrict__ e2u,
        const float* __restrict__ x0, float* __restrict__ xsum0,
        float* __restrict__ outnode, int last) {
    __shared__ float2 sb[4][64];
    int u = threadIdx.x >> 6, lane = threadIdx.x & 63;
    int t = u & 1;
    int n = blockIdx.x * 2 + (u >> 1);
    int r = t * N_ + n;
    int c = cntNE[r];
    float2 g = gather64(ye2u, adjNE + (size_t)r * CAP, c, lane);
    float dv = dVis[r];
    float e0 = dv * g.x; e0 = e0 >= 0.f ? e0 : 0.01f * e0;
    float e1 = dv * g.y; e1 = e1 >= 0.f ? e1 : 0.01f * e1;
    e2u[(size_t)r * UPR + lane] = pack2(e0, e1);
    float2 mine = {e0, e1};
    sb[u][lane] = mine;
    __syncthreads();
    if (t == 0) {
        float2 o2 = sb[u | 1][lane];
        float2 xnew = {e0 + o2.x, e1 + o2.y};
        size_t i = (size_t)n * UPR + lane;
        if (!last) ((float2*)xsum0)[i] = xnew;
        else {
            float2 xv = ((const float2*)x0)[i];
            float2 xs = ((const float2*)xsum0)[i];
            float2 o = {(xv.x + xs.x + xnew.x) * (1.0f / 3.0f),
                        (xv.y + xs.y + xnew.y) * (1.0f / 3.0f)};
            ((float2*)outnode)[i] = o;
        }
    }
}

// node 4: xw layer 1 (blocks 0-1023) || o layer 0 (blocks 1024-3071).
__global__ __launch_bounds__(256) void k_xw1_o0(const float* __restrict__ xsum0,
        const float* __restrict__ W, const float* __restrict__ b,
        unsigned* __restrict__ y2u,
        const unsigned* __restrict__ e2u, const int* __restrict__ cntEN,
        const unsigned* __restrict__ adjEN, float* __restrict__ revacc) {
    __shared__ float s_xs[32 * 36];
    __shared__ float s_ws[32 * 32];
    __shared__ float2 sb[4][64];
    int bid = blockIdx.x;
    if (bid < 1024) {
        xw_tile32(bid, 1, xsum0, W, b, y2u, s_xs, s_ws);
    } else {
        int u = threadIdx.x >> 6, lane = threadIdx.x & 63;
        int e = (bid - 1024) * 2 + (u >> 1);
        o_unit(e, u, lane, e2u, cntEN, adjEN, (float2*)revacc, nullptr, 0, sb);
    }
}

// node 7: o layer 1.
__global__ __launch_bounds__(256) void k_o(const unsigned* __restrict__ e2u,
        const int* __restrict__ cntEN, const unsigned* __restrict__ adjEN,
        float* __restrict__ revacc, float* __restrict__ outrev) {
    __shared__ float2 sb[4][64];
    int u = threadIdx.x >> 6, lane = threadIdx.x & 63;
    int e = blockIdx.x * 2 + (u >> 1);
    o_unit(e, u, lane, e2u, cntEN, adjEN, (float2*)revacc, (float2*)outrev, 1, sb);
}

// ---------------------------------------------------------------------------
extern "C" void kernel_launch(void* const* d_in, const int* in_sizes, int n_in,
                              void* d_out, int out_size, void* d_ws, size_t ws_size,
                              hipStream_t stream) {
    const float* x = (const float*)d_in[0];
    const float* H = (const float*)d_in[1];
    const float* W = (const float*)d_in[2];
    const float* b = (const float*)d_in[3];
    float* outnode = (float*)d_out;
    float* outrev  = (float*)d_out + (size_t)N_ * D_;

    char* p = (char*)d_ws;
    auto alloc = [&](size_t bytes) {
        char* r = p;
        p += (bytes + 255) & ~(size_t)255;
        return r;
    };
    float*    dVis   = (float*)alloc(((size_t)T_ * N_ + 1) * 4);
    int*      cntNE  = (int*)  alloc((size_t)T_ * N_ * 4);
    int*      cntENp = (int*)  alloc(((size_t)T_ * E_ + 1) * 16 * 4);
    int*      cntEN  = (int*)  alloc(((size_t)T_ * E_ + 1) * 4);   // dense copy
    int*      adjNE  = (int*)  alloc((size_t)T_ * N_ * CAP * 4);
    unsigned* adjEN  = (unsigned*)alloc(((size_t)T_ * E_ + 1) * CAP * 4);
    unsigned* y2u    = (unsigned*)alloc((size_t)(SENT + 1) * UPR * 4);
    unsigned* ye2u   = (unsigned*)alloc((size_t)(SENT + 1) * UPR * 4);
    unsigned* e2u    = (unsigned*)alloc((size_t)(SENT + 1) * UPR * 4);
    float*    xsum0  = (float*)alloc((size_t)N_ * D_ * 4);
    float*    revacc = (float*)alloc((size_t)E_ * D_ * 4);

    // 8-node chain
    k_zero0<<<513, 256, 0, stream>>>(cntENp, adjEN, ye2u, e2u);
    k_scan_inv_xw0<<<2048 + 1024, 256, 0, stream>>>(H, dVis, cntNE, adjNE,
            cntENp, adjEN, x, W, b, y2u);
    k_ye_w0<<<2048, 256, 0, stream>>>(y2u, cntENp, adjEN, ye2u, cntEN);
    k_e<<<2048, 256, 0, stream>>>(ye2u, dVis, cntNE, adjNE, e2u, x, xsum0,
                                  outnode, 0);
    k_xw1_o0<<<1024 + 2048, 256, 0, stream>>>(xsum0, W, b, y2u,
            e2u, cntEN, adjEN, revacc);
    k_ye_w1<<<2048, 256, 0, stream>>>(y2u, cntEN, adjEN, ye2u);
    k_e<<<2048, 256, 0, stream>>>(ye2u, dVis, cntNE, adjNE, e2u, x, xsum0,
                                  outnode, 1);
    k_o<<<2048, 256, 0, stream>>>(e2u, cntEN, adjEN, revacc, outrev);
}